// Round 14
// baseline (366.723 us; speedup 1.0000x reference)
//
#include <hip/hip_runtime.h>
#include <hip/hip_fp16.h>

// Problem constants
constexpr int QN  = 10001;   // questions (Q+1)
constexpr int BB  = 512;     // batch
constexpr int TT  = 200;     // seq len
constexpr int QPB = 32;      // questions per block in k_perq

__device__ __forceinline__ float sigm(float x) { return 1.f / (1.f + __expf(-x)); }
__device__ __forceinline__ float tanh_fast(float x) { return 1.f - 2.f / (1.f + __expf(2.f * x)); }

// f32 pair -> packed f16x2 (RTNE via v_cvt_f16_f32 default rounding)
__device__ __forceinline__ unsigned packh_rtne(float lo, float hi) {
    return ((unsigned)__half_as_ushort(__float2half(hi)) << 16) |
            (unsigned)__half_as_ushort(__float2half(lo));
}
__device__ __forceinline__ float h2f_lo(unsigned short u) {
    return __half2float(__ushort_as_half(u));
}

typedef _Float16 half2_t __attribute__((ext_vector_type(2)));
typedef float f4v __attribute__((ext_vector_type(4)));
__device__ __forceinline__ half2_t u2h(unsigned u) {
    union { unsigned u; half2_t h; } x; x.u = u; return x.h;
}

// packed-f16 dot2: acc += w.lo*h.lo + w.hi*h.hi
#if __has_builtin(__builtin_amdgcn_fdot2)
__device__ __forceinline__ float fdot2u(unsigned wu, unsigned hu, float acc) {
    return __builtin_amdgcn_fdot2(u2h(wu), u2h(hu), acc, false);
}
#else
__device__ __forceinline__ float fdot2u(unsigned wu, unsigned hu, float acc) {
    float wlo = __half2float(__ushort_as_half((unsigned short)(wu & 0xffffu)));
    float whi = __half2float(__ushort_as_half((unsigned short)(wu >> 16)));
    float hlo = __half2float(__ushort_as_half((unsigned short)(hu & 0xffffu)));
    float hhi = __half2float(__ushort_as_half((unsigned short)(hu >> 16)));
    return acc + wlo * hlo + whi * hhi;
}
#endif

// ---------------------------------------------------------------------------
// Kernel 1: tiny precomputed tables. T_it/T_ut/T_nh/T_na INTERLEAVED
// [idx][lane][3]; T_c linear (consumed only by k_perq).
// ---------------------------------------------------------------------------
__global__ void k_tables(const float* __restrict__ E_c, const float* __restrict__ E_it,
                         const float* __restrict__ E_ut, const float* __restrict__ E_nh,
                         const float* __restrict__ W_fuse, const float* __restrict__ b_fuse,
                         const float* __restrict__ W_ih, const float* __restrict__ b_ih,
                         float* __restrict__ T_c, float* __restrict__ T_it,
                         float* __restrict__ T_ut, float* __restrict__ T_nh, float* __restrict__ T_na,
                         float* __restrict__ bias0, float* __restrict__ Vcorr)
{
    int blk = blockIdx.x, j = threadIdx.x; // 192 threads
    __shared__ float s_e[64];
    __shared__ float s_t[64];
    const int ilv = (j & 63) * 3 + (j >> 6);   // interleaved slot for gate-row j

    if (blk < 201) {
        if (j < 64) s_e[j] = E_c[blk * 64 + j];
        __syncthreads();
        float a = 0.f;
        #pragma unroll
        for (int k = 0; k < 64; k++) a += W_ih[j * 320 + 64 + k] * s_e[k];
        T_c[blk * 192 + j] = a;             // linear
    } else if (blk < 302) {
        int r = blk - 201;
        if (j < 64) s_e[j] = E_it[r * 64 + j];
        __syncthreads();
        float a = 0.f;
        #pragma unroll
        for (int k = 0; k < 64; k++) a += W_ih[j * 320 + 192 + k] * s_e[k];
        T_it[r * 192 + ilv] = a;            // interleaved
    } else if (blk < 605) {
        int which = (blk - 302) / 101;
        int r     = (blk - 302) % 101;
        const float* E = (which == 0) ? E_ut : E_nh;
        int fofs = which * 64;
        if (j < 64) s_e[j] = E[r * 64 + j];
        __syncthreads();
        if (j < 64) {
            float a = 0.f;
            #pragma unroll
            for (int d = 0; d < 64; d++) a += W_fuse[j * 192 + fofs + d] * s_e[d];
            s_t[j] = a;
        }
        __syncthreads();
        float a = 0.f;
        #pragma unroll
        for (int e = 0; e < 64; e++) a += W_ih[j * 320 + 256 + e] * s_t[e];
        float* outp = (which == 0) ? T_ut : ((which == 1) ? T_nh : T_na);
        outp[r * 192 + ilv] = a;            // interleaved
    } else {
        float a = b_ih[j];
        #pragma unroll
        for (int e = 0; e < 64; e++) a += W_ih[j * 320 + 256 + e] * b_fuse[e];
        bias0[j] = a;
        float v = 0.f;
        #pragma unroll
        for (int k = 0; k < 64; k++) v += W_ih[j * 320 + 128 + k];
        Vcorr[j] = v;
    }
}

// ---------------------------------------------------------------------------
// Kernel 2: per-question precompute (r9 form). Xq written INTERLEAVED.
// ---------------------------------------------------------------------------
__global__ void __launch_bounds__(192) k_perq(
    const float* __restrict__ E_q, const float* __restrict__ W_ih,
    const float* __restrict__ qd_W1, const float* __restrict__ qd_b1,
    const float* __restrict__ qd_W2, const float* __restrict__ qd_b2,
    const float* __restrict__ dc_W1, const float* __restrict__ dc_b1,
    const float* __restrict__ dc_W2, const float* __restrict__ dc_b2,
    const int* __restrict__ q2c, const int* __restrict__ q2cm,
    const float* __restrict__ T_c,
    float* __restrict__ Xq, float* __restrict__ disc,
    float* __restrict__ qds, float* __restrict__ wdk)
{
    __shared__ float s_wbuf[192 * 66];
    __shared__ float s_qe[QPB][64];
    __shared__ float s_wq[QPB][4];
    __shared__ int   s_cq[QPB][4];
    __shared__ float s_hidw[3][136];

    const int tid = threadIdx.x, w = tid >> 6, l = tid & 63;
    const int q0 = blockIdx.x * QPB;

    for (int i = tid; i < 132 * 64; i += 192)
        s_wbuf[(i >> 6) * 66 + (i & 63)] = qd_W1[i];
    for (int i = tid; i < 32 * 64; i += 192)
        s_wbuf[(132 + (i >> 6)) * 66 + (i & 63)] = dc_W1[i];
    for (int i = tid; i < QPB * 64; i += 192) {
        int qq = i >> 6, q = q0 + qq;
        s_qe[qq][i & 63] = E_q[(q < QN ? q : 0) * 64 + (i & 63)];
    }
    __syncthreads();

    for (int qq = w; qq < QPB; qq += 3) {
        int q = q0 + qq;
        bool valid = q < QN;
        int qc = valid ? q : 0;
        int cc[4], mm[4];
        #pragma unroll
        for (int k = 0; k < 4; k++) { cc[k] = q2c[qc * 4 + k]; mm[k] = q2cm[qc * 4 + k]; }

        float qe[64];
        #pragma unroll
        for (int k4 = 0; k4 < 16; k4++) {
            float4 v = *(const float4*)(&s_qe[qq][k4 * 4]);
            qe[4 * k4] = v.x; qe[4 * k4 + 1] = v.y; qe[4 * k4 + 2] = v.z; qe[4 * k4 + 3] = v.w;
        }

        auto rowdot = [&](int r) {
            const float* wr = s_wbuf + r * 66;
            float a = 0.f;
            #pragma unroll
            for (int jj = 0; jj < 32; jj++) {
                float2 ww = *(const float2*)(wr + 2 * jj);
                a += ww.x * qe[2 * jj] + ww.y * qe[2 * jj + 1];
            }
            return a;
        };

        s_hidw[w][l]      = fmaxf(rowdot(l)      + qd_b1[l],      0.f);
        s_hidw[w][64 + l] = fmaxf(rowdot(64 + l) + qd_b1[64 + l], 0.f);
        if (l < 4)
            s_hidw[w][128 + l] = fmaxf(rowdot(128 + l) + qd_b1[128 + l], 0.f);
        float dch = 0.f;
        if (l < 32) dch = fmaxf(rowdot(132 + l) + dc_b1[l], 0.f);

        int g = l >> 4, li = l & 15;
        int c = cc[g];
        float acc = 0.f;
        #pragma unroll
        for (int i = 0; i < 9; i++) {
            int m = li + 16 * i;
            if (m < 132) acc += qd_W2[c * 132 + m] * s_hidw[w][m];
        }
        acc += __shfl_xor(acc, 1); acc += __shfl_xor(acc, 2);
        acc += __shfl_xor(acc, 4); acc += __shfl_xor(acc, 8);
        float r0 = __shfl(acc, 0), r1 = __shfl(acc, 16);
        float r2 = __shfl(acc, 32), r3 = __shfl(acc, 48);

        float raw[4] = { sigm(r0 + qd_b2[cc[0]]), sigm(r1 + qd_b2[cc[1]]),
                         sigm(r2 + qd_b2[cc[2]]), sigm(r3 + qd_b2[cc[3]]) };
        float rel[4];
        #pragma unroll
        for (int k = 0; k < 4; k++) rel[k] = raw[k] * (float)mm[k];
        float sr = rel[0] + rel[1] + rel[2] + rel[3] + 1e-6f;

        float qsum = 0.f, wdv[4];
        #pragma unroll
        for (int k = 0; k < 4; k++) {
            float wd = 0.f;
            if (mm[k]) {
                bool dup = false;
                for (int jj = 0; jj < k; jj++)
                    if (mm[jj] && cc[jj] == cc[k]) dup = true;
                if (!dup) { wd = 1.f; qsum += raw[k]; }
            }
            wdv[k] = wd;
        }
        if (l < 4) { s_wq[qq][l] = rel[l] / sr; s_cq[qq][l] = cc[l]; }
        if (valid) {
            if (l < 4) wdk[q * 4 + l] = wdv[l];
            if (l == 0) qds[q] = qsum;
        }

        float dv = (l < 32) ? dch * dc_W2[l] : 0.f;
        dv += __shfl_xor(dv, 1);  dv += __shfl_xor(dv, 2);
        dv += __shfl_xor(dv, 4);  dv += __shfl_xor(dv, 8);
        dv += __shfl_xor(dv, 16);
        if (valid && l == 0) disc[q] = sigm(dv + dc_b2[0]) * 10.f;
    }

    __syncthreads();
    for (int i = tid; i < 192 * 64; i += 192) {
        int r = i >> 6, k = i & 63;
        s_wbuf[r * 66 + k] = W_ih[r * 320 + k];
    }
    __syncthreads();

    for (int qq = w; qq < QPB; qq += 3) {
        int q = q0 + qq;
        if (q >= QN) continue;

        float qe[64];
        #pragma unroll
        for (int k4 = 0; k4 < 16; k4++) {
            float4 v = *(const float4*)(&s_qe[qq][k4 * 4]);
            qe[4 * k4] = v.x; qe[4 * k4 + 1] = v.y; qe[4 * k4 + 2] = v.z; qe[4 * k4 + 3] = v.w;
        }
        float wq[4]; int cq[4];
        #pragma unroll
        for (int k = 0; k < 4; k++) { wq[k] = s_wq[qq][k]; cq[k] = s_cq[qq][k]; }

        #pragma unroll
        for (int rr = 0; rr < 3; rr++) {
            int row = rr * 64 + l;
            const float* wr = s_wbuf + row * 66;
            float a = 0.f;
            #pragma unroll
            for (int jj = 0; jj < 32; jj++) {
                float2 ww = *(const float2*)(wr + 2 * jj);
                a += ww.x * qe[2 * jj] + ww.y * qe[2 * jj + 1];
            }
            #pragma unroll
            for (int k = 0; k < 4; k++) a += wq[k] * T_c[cq[k] * 192 + row];
            Xq[q * 192 + l * 3 + rr] = a;   // interleaved
        }
    }
}

// ---------------------------------------------------------------------------
// Kernel 3 v14 = v13 + amdgpu_num_vgpr(256). r13's decisive counter: VGPR=132
// despite a 176+ register working set -> allocator spilled the weights /
// in-flight sets to scratch. num_vgpr grants the registers directly.
// ---------------------------------------------------------------------------
__global__ void
__launch_bounds__(64)
__attribute__((amdgpu_num_vgpr(256), amdgpu_waves_per_eu(1, 1)))
k_gru(
    const float* __restrict__ W_hh, const float* __restrict__ b_hh,
    const float* __restrict__ XqI, const float* __restrict__ TitI, const float* __restrict__ TutI,
    const float* __restrict__ TnhI, const float* __restrict__ TnaI,
    const float* __restrict__ b0, const float* __restrict__ vc,
    const int* __restrict__ qseq, const int* __restrict__ cseq, const int* __restrict__ itseq,
    const int* __restrict__ utseq, const int* __restrict__ nhseq, const int* __restrict__ naseq,
    float* __restrict__ latent)
{
    const int j = threadIdx.x, b = blockIdx.x;
    const int j3 = 3 * j;

    __shared__ unsigned s_hp[32];     // h as packed f16 pairs (128 B)
    __shared__ int s_ix[6 * TT];      // q | c | it | ut | nh | na

    const int base = b * TT;
    for (int i = j; i < TT; i += 64) {
        s_ix[i]          = qseq[base + i];
        s_ix[TT + i]     = cseq[base + i];
        s_ix[2 * TT + i] = itseq[base + i];
        s_ix[3 * TT + i] = utseq[base + i];
        s_ix[4 * TT + i] = nhseq[base + i];
        s_ix[5 * TT + i] = naseq[base + i];
    }

    // lane j's three gate rows of W_hh, packed f16: 96 VGPRs
    unsigned wr[32], wz[32], wn[32];
    {
        const float4* p0 = (const float4*)(W_hh + j * 64);
        const float4* p1 = (const float4*)(W_hh + (64 + j) * 64);
        const float4* p2 = (const float4*)(W_hh + (128 + j) * 64);
        #pragma unroll
        for (int k = 0; k < 16; k++) {
            float4 a = p0[k], bq = p1[k], c = p2[k];
            wr[2 * k] = packh_rtne(a.x, a.y);  wr[2 * k + 1] = packh_rtne(a.z, a.w);
            wz[2 * k] = packh_rtne(bq.x, bq.y); wz[2 * k + 1] = packh_rtne(bq.z, bq.w);
            wn[2 * k] = packh_rtne(c.x, c.y);  wn[2 * k + 1] = packh_rtne(c.z, c.w);
        }
    }
    #pragma unroll
    for (int k = 0; k < 32; k++)
        asm volatile("" : "+v"(wr[k]), "+v"(wz[k]), "+v"(wn[k]));

    const float bhr = b_hh[j], bhz = b_hh[64 + j], bhn = b_hh[128 + j];
    const float b0r = b0[j],   b0z = b0[64 + j],   b0n = b0[128 + j];
    const float vcr = vc[j],   vcz = vc[64 + j],   vcn = vc[128 + j];

    if (j < 32) s_hp[j] = 0u;
    float hj = 0.f;

    // 4 static in-flight sets, 5 dwordx4 each (.xyz = r,z,n rows; .w junk)
    f4v A0, A1, A2, A3, A4;  float cA;
    f4v B0, B1, B2, B3, B4;  float cB;
    f4v C0, C1, C2, C3, C4;  float cC;
    f4v D0, D1, D2, D3, D4;  float cD;

#define GISSUE(P, CC, tt) { \
        int q_ = s_ix[tt], c_ = s_ix[TT + tt], it_ = s_ix[2 * TT + tt]; \
        int ut_ = s_ix[3 * TT + tt], nh_ = s_ix[4 * TT + tt], na_ = s_ix[5 * TT + tt]; \
        CC = (float)c_; \
        asm volatile("global_load_dwordx4 %0, %1, off" : "=v"(P##0) : "v"(XqI  + q_  * 192 + j3)); \
        asm volatile("global_load_dwordx4 %0, %1, off" : "=v"(P##1) : "v"(TitI + it_ * 192 + j3)); \
        asm volatile("global_load_dwordx4 %0, %1, off" : "=v"(P##2) : "v"(TutI + ut_ * 192 + j3)); \
        asm volatile("global_load_dwordx4 %0, %1, off" : "=v"(P##3) : "v"(TnhI + nh_ * 192 + j3)); \
        asm volatile("global_load_dwordx4 %0, %1, off" : "=v"(P##4) : "v"(TnaI + na_ * 192 + j3)); \
    }

#define STEP(P, CC, tcur, WN, REF) { \
        asm volatile("s_waitcnt vmcnt(" WN ")" ::: "memory"); \
        float xr = b0r + CC * vcr + ((((P##0).x + (P##1).x) + ((P##2).x + (P##3).x)) + (P##4).x); \
        float xz = b0z + CC * vcz + ((((P##0).y + (P##1).y) + ((P##2).y + (P##3).y)) + (P##4).y); \
        float xn = b0n + CC * vcn + ((((P##0).z + (P##1).z) + ((P##2).z + (P##3).z)) + (P##4).z); \
        asm volatile("" :: "v"((P##0).w), "v"((P##1).w), "v"((P##2).w), "v"((P##3).w), "v"((P##4).w)); \
        if (REF) GISSUE(P, CC, (tcur) + 4); \
        float ar0 = 0.f, ar1 = 0.f, ar2 = 0.f, ar3 = 0.f; \
        float az0 = 0.f, az1 = 0.f, az2 = 0.f, az3 = 0.f; \
        float an0 = 0.f, an1 = 0.f, an2 = 0.f, an3 = 0.f; \
        const uint4* hp4 = (const uint4*)s_hp; \
        _Pragma("unroll") \
        for (int k4 = 0; k4 < 8; k4++) { \
            uint4 hh = hp4[k4]; \
            ar0 = fdot2u(wr[4 * k4 + 0], hh.x, ar0); \
            ar1 = fdot2u(wr[4 * k4 + 1], hh.y, ar1); \
            ar2 = fdot2u(wr[4 * k4 + 2], hh.z, ar2); \
            ar3 = fdot2u(wr[4 * k4 + 3], hh.w, ar3); \
            az0 = fdot2u(wz[4 * k4 + 0], hh.x, az0); \
            az1 = fdot2u(wz[4 * k4 + 1], hh.y, az1); \
            az2 = fdot2u(wz[4 * k4 + 2], hh.z, az2); \
            az3 = fdot2u(wz[4 * k4 + 3], hh.w, az3); \
            an0 = fdot2u(wn[4 * k4 + 0], hh.x, an0); \
            an1 = fdot2u(wn[4 * k4 + 1], hh.y, an1); \
            an2 = fdot2u(wn[4 * k4 + 2], hh.z, an2); \
            an3 = fdot2u(wn[4 * k4 + 3], hh.w, an3); \
        } \
        float ar = ((ar0 + ar1) + (ar2 + ar3)) + bhr; \
        float az = ((az0 + az1) + (az2 + az3)) + bhz; \
        float an = ((an0 + an1) + (an2 + an3)) + bhn; \
        float r = sigm(xr + ar); \
        float z = sigm(xz + az); \
        float n = tanh_fast(xn + r * an); \
        hj = (1.f - z) * n + z * hj; \
        latent[(size_t)(base + (tcur)) * 64 + j] = hj; \
        float hnb = __shfl_xor(hj, 1); \
        unsigned pk = (j & 1) ? packh_rtne(hnb, hj) : packh_rtne(hj, hnb); \
        if (!(j & 1)) s_hp[j >> 1] = pk; \
    }

    GISSUE(A, cA, 0);
    GISSUE(B, cB, 1);
    GISSUE(C, cC, 2);
    GISSUE(D, cD, 3);

    for (int t = 0; t < TT - 4; t += 4) {
        STEP(A, cA, t,     "15", 1);
        STEP(B, cB, t + 1, "15", 1);
        STEP(C, cC, t + 2, "15", 1);
        STEP(D, cD, t + 3, "15", 1);
    }
    STEP(A, cA, TT - 4, "15", 0);
    STEP(B, cB, TT - 3, "10", 0);
    STEP(C, cC, TT - 2, "5",  0);
    STEP(D, cD, TT - 1, "0",  0);
#undef STEP
#undef GISSUE
}

// ---------------------------------------------------------------------------
// Kernel 4 v3: WAVE-PER-TOKEN readout. No per-thread l[64] array (r13 tail
// analysis: suspected scratch-thrash). la_W1 rows packed f16 in REGISTERS
// (64 uints/lane, sourced from LDS so not remat-able), la_W2 f16 in LDS
// (54 KB region reused for the la_W1 f32 staging), latent broadcast via
// per-wave packed LDS, fdot2 dots, shuffle-reduce.
// ---------------------------------------------------------------------------
__global__ void __launch_bounds__(256, 1) k_final(
    const float* __restrict__ latent, const int* __restrict__ qseq,
    const float* __restrict__ la_W1, const float* __restrict__ la_b1,
    const float* __restrict__ la_W2, const float* __restrict__ la_b2,
    const int* __restrict__ q2c,
    const float* __restrict__ disc, const float* __restrict__ qds,
    const float* __restrict__ wdk, float* __restrict__ out)
{
    __shared__ float s_rawf[13600];        // 54.4 KB: phase1 la_W1 f32 [132][67]; phase2 la_W2 f16 [200][136]
    __shared__ unsigned s_w1t[4][33];      // packed rows 128..131
    __shared__ unsigned s_lat[4][36];      // per-wave packed latent

    const int tid = threadIdx.x, wv = tid >> 6, l = tid & 63;

    // phase 1: stage la_W1 f32 with pad-67 rows (conflict-spread reads)
    for (int i = tid; i < 132 * 64; i += 256)
        s_rawf[(i >> 6) * 67 + (i & 63)] = la_W1[i];
    __syncthreads();

    // pack lane's two rows (l, 64+l) to f16 registers; rows 128-131 to LDS
    unsigned w1a[32], w1b[32];
    {
        const float* r0 = s_rawf + l * 67;
        const float* r1 = s_rawf + (64 + l) * 67;
        #pragma unroll
        for (int k = 0; k < 32; k++) {
            w1a[k] = packh_rtne(r0[2 * k], r0[2 * k + 1]);
            w1b[k] = packh_rtne(r1[2 * k], r1[2 * k + 1]);
        }
    }
    for (int i = tid; i < 4 * 32; i += 256) {
        int row = i >> 5, k = i & 31;
        s_w1t[row][k] = packh_rtne(s_rawf[(128 + row) * 67 + 2 * k],
                                   s_rawf[(128 + row) * 67 + 2 * k + 1]);
    }
    #pragma unroll
    for (int k = 0; k < 32; k++)
        asm volatile("" : "+v"(w1a[k]), "+v"(w1b[k]));
    __syncthreads();

    // phase 2: overwrite region with la_W2 as f16 [200][136]
    unsigned short* w2v = (unsigned short*)s_rawf;
    for (int i = tid; i < 200 * 132; i += 256) {
        int c = i / 132, m = i - c * 132;
        w2v[c * 136 + m] = __half_as_ushort(__float2half(la_W2[i]));
    }
    __syncthreads();

    // per-lane invariants
    const float bl0 = la_b1[l], bl1 = la_b1[64 + l];
    const float bl2 = (l < 4) ? la_b1[128 + l] : 0.f;

    const int nTok = BB * (TT - 1);
    const int waveId = blockIdx.x * 4 + wv;
    const int nWaves = gridDim.x * 4;

    for (int tok = waveId; tok < nTok; tok += nWaves) {
        int b = tok / (TT - 1), t = tok - b * (TT - 1);

        // latent broadcast: coalesced read -> packed f16 in per-wave LDS
        float lv = latent[(size_t)(b * TT + t) * 64 + l];
        float lo = __shfl_xor(lv, 1);
        if (!(l & 1)) s_lat[wv][l >> 1] = packh_rtne(lv, lo);
        asm volatile("s_waitcnt lgkmcnt(0)" ::: "memory");

        uint4 L[8];
        {
            const uint4* lp = (const uint4*)s_lat[wv];
            #pragma unroll
            for (int k4 = 0; k4 < 8; k4++) L[k4] = lp[k4];
        }

        // hidden rows l and 64+l via fdot2 (4 accumulators each)
        float a0 = 0.f, a1 = 0.f, a2 = 0.f, a3 = 0.f;
        float c0a = 0.f, c1a = 0.f, c2a = 0.f, c3a = 0.f;
        #pragma unroll
        for (int k4 = 0; k4 < 8; k4++) {
            uint4 hh = L[k4];
            a0  = fdot2u(w1a[4 * k4 + 0], hh.x, a0);
            a1  = fdot2u(w1a[4 * k4 + 1], hh.y, a1);
            a2  = fdot2u(w1a[4 * k4 + 2], hh.z, a2);
            a3  = fdot2u(w1a[4 * k4 + 3], hh.w, a3);
            c0a = fdot2u(w1b[4 * k4 + 0], hh.x, c0a);
            c1a = fdot2u(w1b[4 * k4 + 1], hh.y, c1a);
            c2a = fdot2u(w1b[4 * k4 + 2], hh.z, c2a);
            c3a = fdot2u(w1b[4 * k4 + 3], hh.w, c3a);
        }
        float hm0 = fmaxf(((a0 + a1) + (a2 + a3)) + bl0, 0.f);
        float hm1 = fmaxf(((c0a + c1a) + (c2a + c3a)) + bl1, 0.f);

        // rows 128..131 on lanes 0..3
        float hm2 = 0.f;
        if (l < 4) {
            float h = 0.f;
            const unsigned* wt = s_w1t[l];
            const unsigned* lu = (const unsigned*)s_lat[wv];
            #pragma unroll
            for (int k = 0; k < 32; k++) h = fdot2u(wt[k], lu[k], h);
            hm2 = fmaxf(h + bl2, 0.f);
        }

        int q  = qseq[b * TT + t + 1];
        int c0 = q2c[q * 4], c1 = q2c[q * 4 + 1], c2 = q2c[q * 4 + 2], c3 = q2c[q * 4 + 3];

        float u0 = h2f_lo(w2v[c0 * 136 + l]) * hm0 + h2f_lo(w2v[c0 * 136 + 64 + l]) * hm1;
        float u1 = h2f_lo(w2v[c1 * 136 + l]) * hm0 + h2f_lo(w2v[c1 * 136 + 64 + l]) * hm1;
        float u2 = h2f_lo(w2v[c2 * 136 + l]) * hm0 + h2f_lo(w2v[c2 * 136 + 64 + l]) * hm1;
        float u3 = h2f_lo(w2v[c3 * 136 + l]) * hm0 + h2f_lo(w2v[c3 * 136 + 64 + l]) * hm1;
        if (l < 4) {
            u0 += h2f_lo(w2v[c0 * 136 + 128 + l]) * hm2;
            u1 += h2f_lo(w2v[c1 * 136 + 128 + l]) * hm2;
            u2 += h2f_lo(w2v[c2 * 136 + 128 + l]) * hm2;
            u3 += h2f_lo(w2v[c3 * 136 + 128 + l]) * hm2;
        }
        #pragma unroll
        for (int off = 32; off; off >>= 1) {
            u0 += __shfl_xor(u0, off);
            u1 += __shfl_xor(u1, off);
            u2 += __shfl_xor(u2, off);
            u3 += __shfl_xor(u3, off);
        }

        if (l == 0) {
            float w0 = wdk[q * 4], w1 = wdk[q * 4 + 1], w2w = wdk[q * 4 + 2], w3 = wdk[q * 4 + 3];
            float us = w0 * sigm(u0 + la_b2[c0]) + w1 * sigm(u1 + la_b2[c1])
                     + w2w * sigm(u2 + la_b2[c2]) + w3 * sigm(u3 + la_b2[c3]);
            float qs = qds[q];
            float y = disc[q] * (us - qs) / (qs + 1e-6f);
            out[tok] = sigm(y);
        }
    }
}

// ---------------------------------------------------------------------------
extern "C" void kernel_launch(void* const* d_in, const int* in_sizes, int n_in,
                              void* d_out, int out_size, void* d_ws, size_t ws_size,
                              hipStream_t stream)
{
    const float* E_q    = (const float*)d_in[0];
    const float* E_c    = (const float*)d_in[1];
    const float* E_it   = (const float*)d_in[2];
    const float* E_ut   = (const float*)d_in[3];
    const float* E_nh   = (const float*)d_in[4];
    const float* W_fuse = (const float*)d_in[5];
    const float* b_fuse = (const float*)d_in[6];
    const float* W_ih   = (const float*)d_in[7];
    const float* b_ih   = (const float*)d_in[8];
    const float* W_hh   = (const float*)d_in[9];
    const float* b_hh   = (const float*)d_in[10];
    const float* qd_W1  = (const float*)d_in[11];
    const float* qd_b1  = (const float*)d_in[12];
    const float* qd_W2  = (const float*)d_in[13];
    const float* qd_b2  = (const float*)d_in[14];
    const float* la_W1  = (const float*)d_in[15];
    const float* la_b1  = (const float*)d_in[16];
    const float* la_W2  = (const float*)d_in[17];
    const float* la_b2  = (const float*)d_in[18];
    const float* dc_W1  = (const float*)d_in[19];
    const float* dc_b1  = (const float*)d_in[20];
    const float* dc_W2  = (const float*)d_in[21];
    const float* dc_b2  = (const float*)d_in[22];

    int off = (in_sizes[23] == QN * 200) ? 1 : 0;
    const int* qseq  = (const int*)d_in[23 + off];
    const int* cseq  = (const int*)d_in[24 + off];
    const int* itseq = (const int*)d_in[25 + off];
    const int* utseq = (const int*)d_in[26 + off];
    const int* nhseq = (const int*)d_in[27 + off];
    const int* naseq = (const int*)d_in[28 + off];
    const int* q2c   = (const int*)d_in[29 + off];
    const int* q2cm  = (const int*)d_in[30 + off];

    float* ws = (float*)d_ws;
    size_t o = 0;
    float* T_c  = ws + o; o += (size_t)201 * 192 + 4;
    float* Tit  = ws + o; o += (size_t)101 * 192 + 4;   // interleaved (+pad for dwordx4 overread)
    float* Tut  = ws + o; o += (size_t)101 * 192 + 4;
    float* Tnh  = ws + o; o += (size_t)101 * 192 + 4;
    float* Tna  = ws + o; o += (size_t)101 * 192 + 4;
    float* b0   = ws + o; o += 192;
    float* vc   = ws + o; o += 192;
    float* Xq   = ws + o; o += (size_t)QN * 192 + 4;    // interleaved (+pad)
    float* disc = ws + o; o += QN;
    float* qds  = ws + o; o += QN;
    float* wdk  = ws + o; o += (size_t)QN * 4;
    float* latent = ws + o; o += (size_t)BB * TT * 64;

    float* outp = (float*)d_out;

    k_tables<<<606, 192, 0, stream>>>(E_c, E_it, E_ut, E_nh, W_fuse, b_fuse, W_ih, b_ih,
                                      T_c, Tit, Tut, Tnh, Tna, b0, vc);
    k_perq<<<(QN + QPB - 1) / QPB, 192, 0, stream>>>(E_q, W_ih, qd_W1, qd_b1, qd_W2, qd_b2,
                                                     dc_W1, dc_b1, dc_W2, dc_b2, q2c, q2cm, T_c,
                                                     Xq, disc, qds, wdk);
    k_gru<<<BB, 64, 0, stream>>>(W_hh, b_hh, Xq, Tit, Tut, Tnh, Tna, b0, vc,
                                 qseq, cseq, itseq, utseq, nhseq, naseq, latent);
    k_final<<<512, 256, 0, stream>>>(latent, qseq, la_W1, la_b1,
                                     la_W2, la_b2, q2c, disc, qds, wdk, outp);
}

// Round 15
// 328.393 us; speedup vs baseline: 1.1167x; 1.1167x over previous
//
#include <hip/hip_runtime.h>
#include <hip/hip_fp16.h>

// Problem constants
constexpr int QN  = 10001;   // questions (Q+1)
constexpr int BB  = 512;     // batch
constexpr int TT  = 200;     // seq len
constexpr int QPB = 32;      // questions per block in k_perq

__device__ __forceinline__ float sigm(float x) { return 1.f / (1.f + __expf(-x)); }
__device__ __forceinline__ float tanh_fast(float x) { return 1.f - 2.f / (1.f + __expf(2.f * x)); }

// f32 pair -> packed f16x2 (RTNE via v_cvt_f16_f32 default rounding)
__device__ __forceinline__ unsigned packh_rtne(float lo, float hi) {
    return ((unsigned)__half_as_ushort(__float2half(hi)) << 16) |
            (unsigned)__half_as_ushort(__float2half(lo));
}

typedef _Float16 half2_t __attribute__((ext_vector_type(2)));
typedef float f4v __attribute__((ext_vector_type(4)));
__device__ __forceinline__ half2_t u2h(unsigned u) {
    union { unsigned u; half2_t h; } x; x.u = u; return x.h;
}

// packed-f16 dot2: acc += w.lo*h.lo + w.hi*h.hi
#if __has_builtin(__builtin_amdgcn_fdot2)
__device__ __forceinline__ float fdot2u(unsigned wu, unsigned hu, float acc) {
    return __builtin_amdgcn_fdot2(u2h(wu), u2h(hu), acc, false);
}
#else
__device__ __forceinline__ float fdot2u(unsigned wu, unsigned hu, float acc) {
    float wlo = __half2float(__ushort_as_half((unsigned short)(wu & 0xffffu)));
    float whi = __half2float(__ushort_as_half((unsigned short)(wu >> 16)));
    float hlo = __half2float(__ushort_as_half((unsigned short)(hu & 0xffffu)));
    float hhi = __half2float(__ushort_as_half((unsigned short)(hu >> 16)));
    return acc + wlo * hlo + whi * hhi;
}
#endif

// async global->LDS, 16B per lane: LDS dest = base + 16*lane, global src per-lane.
typedef const __attribute__((address_space(1))) void cgv_t;
typedef __attribute__((address_space(3))) void lv_t;
__device__ __forceinline__ void glds16(const float* g, float* l) {
    __builtin_amdgcn_global_load_lds((cgv_t*)g, (lv_t*)l, 16, 0, 0);
}

// ---------------------------------------------------------------------------
// Kernel 1: tiny precomputed tables. T_it/T_ut/T_nh/T_na laid out
// [idx][lane][4] (gate rows r,z,n at lane*4+{0,1,2}; slot 3 pad) so k_gru
// fetches ONE global_load_lds dwordx4 per table. T_c linear (k_perq only).
// ---------------------------------------------------------------------------
__global__ void k_tables(const float* __restrict__ E_c, const float* __restrict__ E_it,
                         const float* __restrict__ E_ut, const float* __restrict__ E_nh,
                         const float* __restrict__ W_fuse, const float* __restrict__ b_fuse,
                         const float* __restrict__ W_ih, const float* __restrict__ b_ih,
                         float* __restrict__ T_c, float* __restrict__ T_it,
                         float* __restrict__ T_ut, float* __restrict__ T_nh, float* __restrict__ T_na,
                         float* __restrict__ bias0, float* __restrict__ Vcorr)
{
    int blk = blockIdx.x, j = threadIdx.x; // 192 threads
    __shared__ float s_e[64];
    __shared__ float s_t[64];
    const int ilv4 = (j & 63) * 4 + (j >> 6);   // [lane][gate] slot, stride-4

    if (blk < 201) {
        if (j < 64) s_e[j] = E_c[blk * 64 + j];
        __syncthreads();
        float a = 0.f;
        #pragma unroll
        for (int k = 0; k < 64; k++) a += W_ih[j * 320 + 64 + k] * s_e[k];
        T_c[blk * 192 + j] = a;             // linear
    } else if (blk < 302) {
        int r = blk - 201;
        if (j < 64) s_e[j] = E_it[r * 64 + j];
        __syncthreads();
        float a = 0.f;
        #pragma unroll
        for (int k = 0; k < 64; k++) a += W_ih[j * 320 + 192 + k] * s_e[k];
        T_it[r * 256 + ilv4] = a;           // stride-4 interleave
    } else if (blk < 605) {
        int which = (blk - 302) / 101;
        int r     = (blk - 302) % 101;
        const float* E = (which == 0) ? E_ut : E_nh;
        int fofs = which * 64;
        if (j < 64) s_e[j] = E[r * 64 + j];
        __syncthreads();
        if (j < 64) {
            float a = 0.f;
            #pragma unroll
            for (int d = 0; d < 64; d++) a += W_fuse[j * 192 + fofs + d] * s_e[d];
            s_t[j] = a;
        }
        __syncthreads();
        float a = 0.f;
        #pragma unroll
        for (int e = 0; e < 64; e++) a += W_ih[j * 320 + 256 + e] * s_t[e];
        float* outp = (which == 0) ? T_ut : ((which == 1) ? T_nh : T_na);
        outp[r * 256 + ilv4] = a;           // stride-4 interleave
    } else {
        float a = b_ih[j];
        #pragma unroll
        for (int e = 0; e < 64; e++) a += W_ih[j * 320 + 256 + e] * b_fuse[e];
        bias0[j] = a;
        float v = 0.f;
        #pragma unroll
        for (int k = 0; k < 64; k++) v += W_ih[j * 320 + 128 + k];
        Vcorr[j] = v;
    }
}

// ---------------------------------------------------------------------------
// Kernel 2: per-question precompute (r9 form). Xq written stride-4.
// ---------------------------------------------------------------------------
__global__ void __launch_bounds__(192) k_perq(
    const float* __restrict__ E_q, const float* __restrict__ W_ih,
    const float* __restrict__ qd_W1, const float* __restrict__ qd_b1,
    const float* __restrict__ qd_W2, const float* __restrict__ qd_b2,
    const float* __restrict__ dc_W1, const float* __restrict__ dc_b1,
    const float* __restrict__ dc_W2, const float* __restrict__ dc_b2,
    const int* __restrict__ q2c, const int* __restrict__ q2cm,
    const float* __restrict__ T_c,
    float* __restrict__ Xq, float* __restrict__ disc,
    float* __restrict__ qds, float* __restrict__ wdk)
{
    __shared__ float s_wbuf[192 * 66];
    __shared__ float s_qe[QPB][64];
    __shared__ float s_wq[QPB][4];
    __shared__ int   s_cq[QPB][4];
    __shared__ float s_hidw[3][136];

    const int tid = threadIdx.x, w = tid >> 6, l = tid & 63;
    const int q0 = blockIdx.x * QPB;

    for (int i = tid; i < 132 * 64; i += 192)
        s_wbuf[(i >> 6) * 66 + (i & 63)] = qd_W1[i];
    for (int i = tid; i < 32 * 64; i += 192)
        s_wbuf[(132 + (i >> 6)) * 66 + (i & 63)] = dc_W1[i];
    for (int i = tid; i < QPB * 64; i += 192) {
        int qq = i >> 6, q = q0 + qq;
        s_qe[qq][i & 63] = E_q[(q < QN ? q : 0) * 64 + (i & 63)];
    }
    __syncthreads();

    for (int qq = w; qq < QPB; qq += 3) {
        int q = q0 + qq;
        bool valid = q < QN;
        int qc = valid ? q : 0;
        int cc[4], mm[4];
        #pragma unroll
        for (int k = 0; k < 4; k++) { cc[k] = q2c[qc * 4 + k]; mm[k] = q2cm[qc * 4 + k]; }

        float qe[64];
        #pragma unroll
        for (int k4 = 0; k4 < 16; k4++) {
            float4 v = *(const float4*)(&s_qe[qq][k4 * 4]);
            qe[4 * k4] = v.x; qe[4 * k4 + 1] = v.y; qe[4 * k4 + 2] = v.z; qe[4 * k4 + 3] = v.w;
        }

        auto rowdot = [&](int r) {
            const float* wr = s_wbuf + r * 66;
            float a = 0.f;
            #pragma unroll
            for (int jj = 0; jj < 32; jj++) {
                float2 ww = *(const float2*)(wr + 2 * jj);
                a += ww.x * qe[2 * jj] + ww.y * qe[2 * jj + 1];
            }
            return a;
        };

        s_hidw[w][l]      = fmaxf(rowdot(l)      + qd_b1[l],      0.f);
        s_hidw[w][64 + l] = fmaxf(rowdot(64 + l) + qd_b1[64 + l], 0.f);
        if (l < 4)
            s_hidw[w][128 + l] = fmaxf(rowdot(128 + l) + qd_b1[128 + l], 0.f);
        float dch = 0.f;
        if (l < 32) dch = fmaxf(rowdot(132 + l) + dc_b1[l], 0.f);

        int g = l >> 4, li = l & 15;
        int c = cc[g];
        float acc = 0.f;
        #pragma unroll
        for (int i = 0; i < 9; i++) {
            int m = li + 16 * i;
            if (m < 132) acc += qd_W2[c * 132 + m] * s_hidw[w][m];
        }
        acc += __shfl_xor(acc, 1); acc += __shfl_xor(acc, 2);
        acc += __shfl_xor(acc, 4); acc += __shfl_xor(acc, 8);
        float r0 = __shfl(acc, 0), r1 = __shfl(acc, 16);
        float r2 = __shfl(acc, 32), r3 = __shfl(acc, 48);

        float raw[4] = { sigm(r0 + qd_b2[cc[0]]), sigm(r1 + qd_b2[cc[1]]),
                         sigm(r2 + qd_b2[cc[2]]), sigm(r3 + qd_b2[cc[3]]) };
        float rel[4];
        #pragma unroll
        for (int k = 0; k < 4; k++) rel[k] = raw[k] * (float)mm[k];
        float sr = rel[0] + rel[1] + rel[2] + rel[3] + 1e-6f;

        float qsum = 0.f, wdv[4];
        #pragma unroll
        for (int k = 0; k < 4; k++) {
            float wd = 0.f;
            if (mm[k]) {
                bool dup = false;
                for (int jj = 0; jj < k; jj++)
                    if (mm[jj] && cc[jj] == cc[k]) dup = true;
                if (!dup) { wd = 1.f; qsum += raw[k]; }
            }
            wdv[k] = wd;
        }
        if (l < 4) { s_wq[qq][l] = rel[l] / sr; s_cq[qq][l] = cc[l]; }
        if (valid) {
            if (l < 4) wdk[q * 4 + l] = wdv[l];
            if (l == 0) qds[q] = qsum;
        }

        float dv = (l < 32) ? dch * dc_W2[l] : 0.f;
        dv += __shfl_xor(dv, 1);  dv += __shfl_xor(dv, 2);
        dv += __shfl_xor(dv, 4);  dv += __shfl_xor(dv, 8);
        dv += __shfl_xor(dv, 16);
        if (valid && l == 0) disc[q] = sigm(dv + dc_b2[0]) * 10.f;
    }

    __syncthreads();
    for (int i = tid; i < 192 * 64; i += 192) {
        int r = i >> 6, k = i & 63;
        s_wbuf[r * 66 + k] = W_ih[r * 320 + k];
    }
    __syncthreads();

    for (int qq = w; qq < QPB; qq += 3) {
        int q = q0 + qq;
        if (q >= QN) continue;

        float qe[64];
        #pragma unroll
        for (int k4 = 0; k4 < 16; k4++) {
            float4 v = *(const float4*)(&s_qe[qq][k4 * 4]);
            qe[4 * k4] = v.x; qe[4 * k4 + 1] = v.y; qe[4 * k4 + 2] = v.z; qe[4 * k4 + 3] = v.w;
        }
        float wq[4]; int cq[4];
        #pragma unroll
        for (int k = 0; k < 4; k++) { wq[k] = s_wq[qq][k]; cq[k] = s_cq[qq][k]; }

        #pragma unroll
        for (int rr = 0; rr < 3; rr++) {
            int row = rr * 64 + l;
            const float* wr = s_wbuf + row * 66;
            float a = 0.f;
            #pragma unroll
            for (int jj = 0; jj < 32; jj++) {
                float2 ww = *(const float2*)(wr + 2 * jj);
                a += ww.x * qe[2 * jj] + ww.y * qe[2 * jj + 1];
            }
            #pragma unroll
            for (int k = 0; k < 4; k++) a += wq[k] * T_c[cq[k] * 192 + row];
            Xq[q * 256 + l * 4 + rr] = a;   // stride-4 interleave
        }
    }
}

// ---------------------------------------------------------------------------
// Kernel 3 v15: one wave per sample; pipeline held in LDS via
// global_load_lds (r14 proof: allocator spills reg-held in-flight sets and
// the spill store forces vmcnt(0) -> pipeline defeated). Five dwordx4
// async loads per step land in one of 4 LDS slots; counted vmcnt keeps a
// true 4-step (~2000cy) load-to-use distance with ZERO in-flight VGPRs.
// Slot values are read + lgkmcnt(0)-fenced BEFORE the slot refill issues.
// ---------------------------------------------------------------------------
__global__ void
__launch_bounds__(64)
__attribute__((amdgpu_waves_per_eu(1, 1)))
k_gru(
    const float* __restrict__ W_hh, const float* __restrict__ b_hh,
    const float* __restrict__ XqI, const float* __restrict__ TitI, const float* __restrict__ TutI,
    const float* __restrict__ TnhI, const float* __restrict__ TnaI,
    const float* __restrict__ b0, const float* __restrict__ vc,
    const int* __restrict__ qseq, const int* __restrict__ cseq, const int* __restrict__ itseq,
    const int* __restrict__ utseq, const int* __restrict__ nhseq, const int* __restrict__ naseq,
    float* __restrict__ latent)
{
    const int j = threadIdx.x, b = blockIdx.x;
    const int j4 = 4 * j;

    __shared__ float s_gb[4][5][64][4];   // 4 slots x 5 tables x 64 lanes x 16B = 20KB
    __shared__ unsigned s_hp[32];         // h as packed f16 pairs (128 B)
    __shared__ int s_ix[6 * TT];          // q | c | it | ut | nh | na

    const int base = b * TT;
    for (int i = j; i < TT; i += 64) {
        s_ix[i]          = qseq[base + i];
        s_ix[TT + i]     = cseq[base + i];
        s_ix[2 * TT + i] = itseq[base + i];
        s_ix[3 * TT + i] = utseq[base + i];
        s_ix[4 * TT + i] = nhseq[base + i];
        s_ix[5 * TT + i] = naseq[base + i];
    }

    // lane j's three gate rows of W_hh, packed f16: 96 VGPRs
    unsigned wr[32], wz[32], wn[32];
    {
        const float4* p0 = (const float4*)(W_hh + j * 64);
        const float4* p1 = (const float4*)(W_hh + (64 + j) * 64);
        const float4* p2 = (const float4*)(W_hh + (128 + j) * 64);
        #pragma unroll
        for (int k = 0; k < 16; k++) {
            float4 a = p0[k], bq = p1[k], c = p2[k];
            wr[2 * k] = packh_rtne(a.x, a.y);  wr[2 * k + 1] = packh_rtne(a.z, a.w);
            wz[2 * k] = packh_rtne(bq.x, bq.y); wz[2 * k + 1] = packh_rtne(bq.z, bq.w);
            wn[2 * k] = packh_rtne(c.x, c.y);  wn[2 * k + 1] = packh_rtne(c.z, c.w);
        }
    }
    #pragma unroll
    for (int k = 0; k < 32; k++)
        asm volatile("" : "+v"(wr[k]), "+v"(wz[k]), "+v"(wn[k]));

    const float bhr = b_hh[j], bhz = b_hh[64 + j], bhn = b_hh[128 + j];
    const float b0r = b0[j],   b0z = b0[64 + j],   b0n = b0[128 + j];
    const float vcr = vc[j],   vcz = vc[64 + j],   vcn = vc[128 + j];

    if (j < 32) s_hp[j] = 0u;
    float hj = 0.f;

    float cA, cB, cC, cD;

#define GISSUE(S, CCV, tt) { \
        int q_ = s_ix[tt], c_ = s_ix[TT + tt], it_ = s_ix[2 * TT + tt]; \
        int ut_ = s_ix[3 * TT + tt], nh_ = s_ix[4 * TT + tt], na_ = s_ix[5 * TT + tt]; \
        CCV = (float)c_; \
        glds16(XqI  + q_  * 256 + j4, &s_gb[S][0][0][0]); \
        glds16(TitI + it_ * 256 + j4, &s_gb[S][1][0][0]); \
        glds16(TutI + ut_ * 256 + j4, &s_gb[S][2][0][0]); \
        glds16(TnhI + nh_ * 256 + j4, &s_gb[S][3][0][0]); \
        glds16(TnaI + na_ * 256 + j4, &s_gb[S][4][0][0]); \
    }

#define STEP(S, CCV, tcur, WN, REF) { \
        asm volatile("s_waitcnt vmcnt(" WN ")" ::: "memory"); \
        f4v g0 = *(const f4v*)&s_gb[S][0][j][0]; \
        f4v g1 = *(const f4v*)&s_gb[S][1][j][0]; \
        f4v g2 = *(const f4v*)&s_gb[S][2][j][0]; \
        f4v g3 = *(const f4v*)&s_gb[S][3][j][0]; \
        f4v g4 = *(const f4v*)&s_gb[S][4][j][0]; \
        asm volatile("s_waitcnt lgkmcnt(0)" ::: "memory"); \
        float xr = b0r + CCV * vcr + (((g0.x + g1.x) + (g2.x + g3.x)) + g4.x); \
        float xz = b0z + CCV * vcz + (((g0.y + g1.y) + (g2.y + g3.y)) + g4.y); \
        float xn = b0n + CCV * vcn + (((g0.z + g1.z) + (g2.z + g3.z)) + g4.z); \
        if (REF) GISSUE(S, CCV, (tcur) + 4); \
        float ar0 = 0.f, ar1 = 0.f, ar2 = 0.f, ar3 = 0.f; \
        float az0 = 0.f, az1 = 0.f, az2 = 0.f, az3 = 0.f; \
        float an0 = 0.f, an1 = 0.f, an2 = 0.f, an3 = 0.f; \
        const uint4* hp4 = (const uint4*)s_hp; \
        _Pragma("unroll") \
        for (int k4 = 0; k4 < 8; k4++) { \
            uint4 hh = hp4[k4]; \
            ar0 = fdot2u(wr[4 * k4 + 0], hh.x, ar0); \
            ar1 = fdot2u(wr[4 * k4 + 1], hh.y, ar1); \
            ar2 = fdot2u(wr[4 * k4 + 2], hh.z, ar2); \
            ar3 = fdot2u(wr[4 * k4 + 3], hh.w, ar3); \
            az0 = fdot2u(wz[4 * k4 + 0], hh.x, az0); \
            az1 = fdot2u(wz[4 * k4 + 1], hh.y, az1); \
            az2 = fdot2u(wz[4 * k4 + 2], hh.z, az2); \
            az3 = fdot2u(wz[4 * k4 + 3], hh.w, az3); \
            an0 = fdot2u(wn[4 * k4 + 0], hh.x, an0); \
            an1 = fdot2u(wn[4 * k4 + 1], hh.y, an1); \
            an2 = fdot2u(wn[4 * k4 + 2], hh.z, an2); \
            an3 = fdot2u(wn[4 * k4 + 3], hh.w, an3); \
        } \
        float ar = ((ar0 + ar1) + (ar2 + ar3)) + bhr; \
        float az = ((az0 + az1) + (az2 + az3)) + bhz; \
        float an = ((an0 + an1) + (an2 + an3)) + bhn; \
        float r = sigm(xr + ar); \
        float z = sigm(xz + az); \
        float n = tanh_fast(xn + r * an); \
        hj = (1.f - z) * n + z * hj; \
        latent[(size_t)(base + (tcur)) * 64 + j] = hj; \
        float hnb = __shfl_xor(hj, 1); \
        unsigned pk = (j & 1) ? packh_rtne(hnb, hj) : packh_rtne(hj, hnb); \
        if (!(j & 1)) s_hp[j >> 1] = pk; \
    }

    GISSUE(0, cA, 0);
    GISSUE(1, cB, 1);
    GISSUE(2, cC, 2);
    GISSUE(3, cD, 3);

    // prologue: exact counted waits (loads+stores retire in order)
    STEP(0, cA, 0, "15", 1);
    STEP(1, cB, 1, "16", 1);
    STEP(2, cC, 2, "17", 1);
    STEP(3, cD, 3, "18", 1);

    for (int t = 4; t <= TT - 8; t += 4) {
        STEP(0, cA, t,     "18", 1);
        STEP(1, cB, t + 1, "18", 1);
        STEP(2, cC, t + 2, "18", 1);
        STEP(3, cD, t + 3, "18", 1);
    }
    STEP(0, cA, TT - 4, "18", 0);
    STEP(1, cB, TT - 3, "12", 0);
    STEP(2, cC, TT - 2, "6",  0);
    STEP(3, cD, TT - 1, "0",  0);
#undef STEP
#undef GISSUE
}

// ---------------------------------------------------------------------------
// Kernel 4: readout with la_W2 staged in LDS as f16 (r11 form — best
// measured; r14's wave-per-token variant was +43us, reverted).
// ---------------------------------------------------------------------------
__global__ void __launch_bounds__(256) k_final(
    const float* __restrict__ latent, const int* __restrict__ qseq,
    const float* __restrict__ la_W1, const float* __restrict__ la_b1,
    const float* __restrict__ la_W2, const float* __restrict__ la_b2,
    const int* __restrict__ q2c,
    const float* __restrict__ disc, const float* __restrict__ qds,
    const float* __restrict__ wdk, float* __restrict__ out)
{
    __shared__ unsigned short s_w2[200 * 132];   // 52.8 KB
    __shared__ float s_b2[200];

    const int tid = threadIdx.x;
    for (int i = tid; i < 200 * 132; i += 256)
        s_w2[i] = __half_as_ushort(__float2half(la_W2[i]));
    for (int i = tid; i < 200; i += 256) s_b2[i] = la_b2[i];
    __syncthreads();

    int o = blockIdx.x * blockDim.x + tid;
    if (o >= BB * (TT - 1)) return;
    int b = o / (TT - 1), t = o - b * (TT - 1);

    const float* lat = latent + (size_t)(b * TT + t) * 64;
    float l[64];
    #pragma unroll
    for (int k4 = 0; k4 < 16; k4++) {
        float4 v = ((const float4*)lat)[k4];
        l[k4 * 4] = v.x; l[k4 * 4 + 1] = v.y; l[k4 * 4 + 2] = v.z; l[k4 * 4 + 3] = v.w;
    }

    int q = qseq[b * TT + t + 1];
    int c0 = q2c[q * 4], c1 = q2c[q * 4 + 1], c2 = q2c[q * 4 + 2], c3 = q2c[q * 4 + 3];
    const unsigned short* w0p = s_w2 + c0 * 132;
    const unsigned short* w1p = s_w2 + c1 * 132;
    const unsigned short* w2p = s_w2 + c2 * 132;
    const unsigned short* w3p = s_w2 + c3 * 132;

    float u0 = 0.f, u1 = 0.f, u2 = 0.f, u3 = 0.f;
    for (int m = 0; m < 132; m++) {
        float a = la_b1[m];
        const float* w = la_W1 + m * 64;
        #pragma unroll
        for (int k = 0; k < 64; k++) a += w[k] * l[k];
        float hm = fmaxf(a, 0.f);
        u0 += __half2float(__ushort_as_half(w0p[m])) * hm;
        u1 += __half2float(__ushort_as_half(w1p[m])) * hm;
        u2 += __half2float(__ushort_as_half(w2p[m])) * hm;
        u3 += __half2float(__ushort_as_half(w3p[m])) * hm;
    }

    float w0 = wdk[q * 4], w1 = wdk[q * 4 + 1], w2 = wdk[q * 4 + 2], w3 = wdk[q * 4 + 3];
    float us = w0 * sigm(u0 + s_b2[c0]) + w1 * sigm(u1 + s_b2[c1])
             + w2 * sigm(u2 + s_b2[c2]) + w3 * sigm(u3 + s_b2[c3]);
    float qs = qds[q];
    float y = disc[q] * (us - qs) / (qs + 1e-6f);
    out[o] = sigm(y);
}

// ---------------------------------------------------------------------------
extern "C" void kernel_launch(void* const* d_in, const int* in_sizes, int n_in,
                              void* d_out, int out_size, void* d_ws, size_t ws_size,
                              hipStream_t stream)
{
    const float* E_q    = (const float*)d_in[0];
    const float* E_c    = (const float*)d_in[1];
    const float* E_it   = (const float*)d_in[2];
    const float* E_ut   = (const float*)d_in[3];
    const float* E_nh   = (const float*)d_in[4];
    const float* W_fuse = (const float*)d_in[5];
    const float* b_fuse = (const float*)d_in[6];
    const float* W_ih   = (const float*)d_in[7];
    const float* b_ih   = (const float*)d_in[8];
    const float* W_hh   = (const float*)d_in[9];
    const float* b_hh   = (const float*)d_in[10];
    const float* qd_W1  = (const float*)d_in[11];
    const float* qd_b1  = (const float*)d_in[12];
    const float* qd_W2  = (const float*)d_in[13];
    const float* qd_b2  = (const float*)d_in[14];
    const float* la_W1  = (const float*)d_in[15];
    const float* la_b1  = (const float*)d_in[16];
    const float* la_W2  = (const float*)d_in[17];
    const float* la_b2  = (const float*)d_in[18];
    const float* dc_W1  = (const float*)d_in[19];
    const float* dc_b1  = (const float*)d_in[20];
    const float* dc_W2  = (const float*)d_in[21];
    const float* dc_b2  = (const float*)d_in[22];

    int off = (in_sizes[23] == QN * 200) ? 1 : 0;
    const int* qseq  = (const int*)d_in[23 + off];
    const int* cseq  = (const int*)d_in[24 + off];
    const int* itseq = (const int*)d_in[25 + off];
    const int* utseq = (const int*)d_in[26 + off];
    const int* nhseq = (const int*)d_in[27 + off];
    const int* naseq = (const int*)d_in[28 + off];
    const int* q2c   = (const int*)d_in[29 + off];
    const int* q2cm  = (const int*)d_in[30 + off];

    float* ws = (float*)d_ws;
    size_t o = 0;
    float* T_c  = ws + o; o += (size_t)201 * 192;
    float* Tit  = ws + o; o += (size_t)101 * 256;   // stride-4 interleaved
    float* Tut  = ws + o; o += (size_t)101 * 256;
    float* Tnh  = ws + o; o += (size_t)101 * 256;
    float* Tna  = ws + o; o += (size_t)101 * 256;
    float* b0   = ws + o; o += 192;
    float* vc   = ws + o; o += 192;
    float* Xq   = ws + o; o += (size_t)QN * 256;    // stride-4 interleaved
    float* disc = ws + o; o += QN;
    float* qds  = ws + o; o += QN;
    float* wdk  = ws + o; o += (size_t)QN * 4;
    float* latent = ws + o; o += (size_t)BB * TT * 64;

    float* outp = (float*)d_out;

    k_tables<<<606, 192, 0, stream>>>(E_c, E_it, E_ut, E_nh, W_fuse, b_fuse, W_ih, b_ih,
                                      T_c, Tit, Tut, Tnh, Tna, b0, vc);
    k_perq<<<(QN + QPB - 1) / QPB, 192, 0, stream>>>(E_q, W_ih, qd_W1, qd_b1, qd_W2, qd_b2,
                                                     dc_W1, dc_b1, dc_W2, dc_b2, q2c, q2cm, T_c,
                                                     Xq, disc, qds, wdk);
    k_gru<<<BB, 64, 0, stream>>>(W_hh, b_hh, Xq, Tit, Tut, Tnh, Tna, b0, vc,
                                 qseq, cseq, itseq, utseq, nhseq, naseq, latent);
    k_final<<<(BB * (TT - 1) + 255) / 256, 256, 0, stream>>>(latent, qseq, la_W1, la_b1,
                                                             la_W2, la_b2, q2c, disc, qds, wdk, outp);
}